// Round 1
// baseline (229.893 us; speedup 1.0000x reference)
//
#include <hip/hip_runtime.h>

// Problem constants (fixed by reference setup_inputs).
#define N 32
#define T 64
#define C 256
#define L 64
#define TC (T * C)                    // 16384 (t,c) pairs per n
#define BLK_PER_N 16                  // blocks along the (t,c) axis per n
#define PAIRS_PER_BLK (TC / BLK_PER_N) // 1024

// Kernel 1: partial[b][n][l] = sum over this block's (t,c) pairs of q[n,t,c,l]*k[t,n,c]
// Mapping: block = 256 threads = 4 waves; each wave splits into 4 quarter-waves of
// 16 lanes; a quarter-wave owns one (t,c) pair per iteration, lane lq loads the
// float4 q[n,t,c, 4*lq .. 4*lq+3] (fully coalesced, 16B/lane) and FMAs against the
// broadcast scalar k[t,n,c].
__global__ __launch_bounds__(256) void scores_partial_kernel(
    const float* __restrict__ q, const float* __restrict__ k,
    float* __restrict__ partial) {
  const int n    = blockIdx.y;
  const int tid  = threadIdx.x;
  const int lane = tid & 63;
  const int wave = tid >> 6;      // 0..3
  const int sub  = lane >> 4;     // quarter-wave within wave, 0..3
  const int lq   = lane & 15;     // lane within quarter-wave -> l-group
  const int g    = wave * 4 + sub; // group id in block, 0..15

  const int p0 = blockIdx.x * PAIRS_PER_BLK;
  const float* qn = q + (size_t)n * TC * L;

  float4 acc = make_float4(0.f, 0.f, 0.f, 0.f);
  for (int i = g; i < PAIRS_PER_BLK; i += 16) {
    const int p = p0 + i;
    const float4 qv = *reinterpret_cast<const float4*>(qn + (size_t)p * L + lq * 4);
    const int t = p >> 8;        // C == 256
    const int c = p & 255;
    const float kv = k[t * (N * C) + n * C + c];  // broadcast within quarter-wave
    acc.x = fmaf(qv.x, kv, acc.x);
    acc.y = fmaf(qv.y, kv, acc.y);
    acc.z = fmaf(qv.z, kv, acc.z);
    acc.w = fmaf(qv.w, kv, acc.w);
  }

  // Sum the 4 quarter-waves of this wave (they hold the same l-groups, different pairs).
  acc.x += __shfl_xor(acc.x, 16); acc.y += __shfl_xor(acc.y, 16);
  acc.z += __shfl_xor(acc.z, 16); acc.w += __shfl_xor(acc.w, 16);
  acc.x += __shfl_xor(acc.x, 32); acc.y += __shfl_xor(acc.y, 32);
  acc.z += __shfl_xor(acc.z, 32); acc.w += __shfl_xor(acc.w, 32);

  // Cross-wave reduction via LDS (1 KB).
  __shared__ float sdata[4 * L];
  if (lane < 16) {
    sdata[wave * L + lq * 4 + 0] = acc.x;
    sdata[wave * L + lq * 4 + 1] = acc.y;
    sdata[wave * L + lq * 4 + 2] = acc.z;
    sdata[wave * L + lq * 4 + 3] = acc.w;
  }
  __syncthreads();
  if (tid < L) {
    const float s = sdata[tid] + sdata[L + tid] + sdata[2 * L + tid] + sdata[3 * L + tid];
    partial[(size_t)blockIdx.x * (N * L) + n * L + tid] = s;  // deterministic, no atomics
  }
}

// Kernel 2: every block (re)computes softmax(scores[n,:]) from the 16 partials
// (4 KB read, L2-hot, redundant but trivial), then computes
// out[t,n,c] = dot(q[n,t,c,:], probs[n,:]) with the same coalesced mapping.
__global__ __launch_bounds__(256) void out_kernel(
    const float* __restrict__ q, const float* __restrict__ partial,
    float* __restrict__ out) {
  const int n   = blockIdx.y;
  const int tid = threadIdx.x;

  __shared__ float probs[L];
  if (tid < L) {  // exactly wave 0
    float s = 0.f;
    #pragma unroll
    for (int b = 0; b < BLK_PER_N; ++b)
      s += partial[(size_t)b * (N * L) + n * L + tid];
    float m = s;
    #pragma unroll
    for (int off = 32; off > 0; off >>= 1) m = fmaxf(m, __shfl_xor(m, off));
    const float e = __expf(s - m);
    float sum = e;
    #pragma unroll
    for (int off = 32; off > 0; off >>= 1) sum += __shfl_xor(sum, off);
    probs[tid] = e / sum;
  }
  __syncthreads();

  const int lane = tid & 63;
  const int wave = tid >> 6;
  const int sub  = lane >> 4;
  const int lq   = lane & 15;
  const int g    = wave * 4 + sub;

  const float4 pv = *reinterpret_cast<const float4*>(&probs[lq * 4]);
  const int p0 = blockIdx.x * PAIRS_PER_BLK;
  const float* qn = q + (size_t)n * TC * L;

  for (int i = g; i < PAIRS_PER_BLK; i += 16) {
    const int p = p0 + i;
    const float4 qv = *reinterpret_cast<const float4*>(qn + (size_t)p * L + lq * 4);
    float d = qv.x * pv.x + qv.y * pv.y + qv.z * pv.z + qv.w * pv.w;
    // Reduce across the 16 lanes of the quarter-wave.
    d += __shfl_xor(d, 1);
    d += __shfl_xor(d, 2);
    d += __shfl_xor(d, 4);
    d += __shfl_xor(d, 8);
    if (lq == 0) {
      const int t = p >> 8;
      const int c = p & 255;
      out[t * (N * C) + n * C + c] = d;
    }
  }
}

extern "C" void kernel_launch(void* const* d_in, const int* in_sizes, int n_in,
                              void* d_out, int out_size, void* d_ws, size_t ws_size,
                              hipStream_t stream) {
  const float* q = (const float*)d_in[0];   // query: (32,64,256,64) fp32
  const float* k = (const float*)d_in[1];   // key:   (64,32,256)    fp32
  float* out = (float*)d_out;               // out:   (64,32,256)    fp32
  float* partial = (float*)d_ws;            // [16][32][64] fp32 = 128 KiB scratch

  dim3 grid(BLK_PER_N, N);                  // 512 blocks x 256 threads
  scores_partial_kernel<<<grid, 256, 0, stream>>>(q, k, partial);
  out_kernel<<<grid, 256, 0, stream>>>(q, partial, out);
}

// Round 2
// 211.627 us; speedup vs baseline: 1.0863x; 1.0863x over previous
//
#include <hip/hip_runtime.h>

// Problem constants (fixed by reference setup_inputs).
#define N 32
#define T 64
#define C 256
#define L 64
#define TC (T * C)                     // 16384 (t,c) pairs per n
#define BLK_PER_N 64                   // blocks along the (t,c) axis per n
#define PAIRS_PER_BLK (TC / BLK_PER_N) // 256

// Kernel 1: partial[b][n][l] = sum over this block's (t,c) pairs of q[n,t,c,l]*k[t,n,c]
// Block = 256 threads = 4 waves = 16 quarter-waves of 16 lanes. A quarter-wave owns
// one (t,c) pair per iteration; lane lq loads float4 q[n,t,c,4lq..4lq+3] (coalesced
// 16B/lane) and FMAs against broadcast k[t,n,c]. 2048 blocks -> 32 waves/CU.
__global__ __launch_bounds__(256, 8) void scores_partial_kernel(
    const float* __restrict__ q, const float* __restrict__ k,
    float* __restrict__ partial) {
  const int n    = blockIdx.y;
  const int tid  = threadIdx.x;
  const int lane = tid & 63;
  const int wave = tid >> 6;      // 0..3
  const int sub  = lane >> 4;     // quarter-wave within wave, 0..3
  const int lq   = lane & 15;     // lane within quarter-wave -> l-group
  const int g    = wave * 4 + sub; // group id in block, 0..15

  const int p0 = blockIdx.x * PAIRS_PER_BLK;
  const float* qn = q + (size_t)n * TC * L;

  float4 acc = make_float4(0.f, 0.f, 0.f, 0.f);
  #pragma unroll 4
  for (int i = g; i < PAIRS_PER_BLK; i += 16) {   // 16 iterations
    const int p = p0 + i;
    const float4 qv = *reinterpret_cast<const float4*>(qn + (size_t)p * L + lq * 4);
    const int t = p >> 8;        // C == 256
    const int c = p & 255;
    const float kv = k[t * (N * C) + n * C + c];  // broadcast within quarter-wave
    acc.x = fmaf(qv.x, kv, acc.x);
    acc.y = fmaf(qv.y, kv, acc.y);
    acc.z = fmaf(qv.z, kv, acc.z);
    acc.w = fmaf(qv.w, kv, acc.w);
  }

  // Sum the 4 quarter-waves of this wave (same l-groups, different pairs).
  acc.x += __shfl_xor(acc.x, 16); acc.y += __shfl_xor(acc.y, 16);
  acc.z += __shfl_xor(acc.z, 16); acc.w += __shfl_xor(acc.w, 16);
  acc.x += __shfl_xor(acc.x, 32); acc.y += __shfl_xor(acc.y, 32);
  acc.z += __shfl_xor(acc.z, 32); acc.w += __shfl_xor(acc.w, 32);

  // Cross-wave reduction via LDS (1 KB).
  __shared__ float sdata[4 * L];
  if (lane < 16) {
    sdata[wave * L + lq * 4 + 0] = acc.x;
    sdata[wave * L + lq * 4 + 1] = acc.y;
    sdata[wave * L + lq * 4 + 2] = acc.z;
    sdata[wave * L + lq * 4 + 3] = acc.w;
  }
  __syncthreads();
  if (tid < L) {
    const float s = sdata[tid] + sdata[L + tid] + sdata[2 * L + tid] + sdata[3 * L + tid];
    partial[(size_t)blockIdx.x * (N * L) + n * L + tid] = s;  // deterministic, no atomics
  }
}

// Kernel 2: every block recomputes softmax(scores[n,:]) from the 64 partials
// (16 KiB, L2-hot; reduction split across all 4 waves), then computes
// out[t,n,c] = dot(q[n,t,c,:], probs[n,:]) with the same coalesced mapping.
__global__ __launch_bounds__(256, 8) void out_kernel(
    const float* __restrict__ q, const float* __restrict__ partial,
    float* __restrict__ out) {
  const int n    = blockIdx.y;
  const int tid  = threadIdx.x;
  const int lane = tid & 63;
  const int wave = tid >> 6;

  __shared__ float sred[4 * L];
  __shared__ float probs[L];
  {
    // Wave w sums partial blocks b in [16w, 16w+16); lane = l index.
    float s = 0.f;
    #pragma unroll 4
    for (int b = wave * 16; b < wave * 16 + 16; ++b)
      s += partial[(size_t)b * (N * L) + n * L + lane];
    sred[wave * L + lane] = s;
  }
  __syncthreads();
  if (tid < L) {  // wave 0 finishes softmax over l=tid
    float s = sred[tid] + sred[L + tid] + sred[2 * L + tid] + sred[3 * L + tid];
    float m = s;
    #pragma unroll
    for (int off = 32; off > 0; off >>= 1) m = fmaxf(m, __shfl_xor(m, off));
    const float e = __expf(s - m);
    float sum = e;
    #pragma unroll
    for (int off = 32; off > 0; off >>= 1) sum += __shfl_xor(sum, off);
    probs[tid] = e / sum;
  }
  __syncthreads();

  const int sub = lane >> 4;
  const int lq  = lane & 15;
  const int g   = wave * 4 + sub;

  const float4 pv = *reinterpret_cast<const float4*>(&probs[lq * 4]);
  const int p0 = blockIdx.x * PAIRS_PER_BLK;
  const float* qn = q + (size_t)n * TC * L;

  #pragma unroll 4
  for (int i = g; i < PAIRS_PER_BLK; i += 16) {   // 16 iterations
    const int p = p0 + i;
    const float4 qv = *reinterpret_cast<const float4*>(qn + (size_t)p * L + lq * 4);
    float d = qv.x * pv.x + qv.y * pv.y + qv.z * pv.z + qv.w * pv.w;
    // Reduce across the 16 lanes of the quarter-wave.
    d += __shfl_xor(d, 1);
    d += __shfl_xor(d, 2);
    d += __shfl_xor(d, 4);
    d += __shfl_xor(d, 8);
    if (lq == 0) {
      const int t = p >> 8;
      const int c = p & 255;
      out[t * (N * C) + n * C + c] = d;   // lanes 0/16/32/48 hit 4 consecutive floats
    }
  }
}

extern "C" void kernel_launch(void* const* d_in, const int* in_sizes, int n_in,
                              void* d_out, int out_size, void* d_ws, size_t ws_size,
                              hipStream_t stream) {
  const float* q = (const float*)d_in[0];   // query: (32,64,256,64) fp32
  const float* k = (const float*)d_in[1];   // key:   (64,32,256)    fp32
  float* out = (float*)d_out;               // out:   (64,32,256)    fp32
  float* partial = (float*)d_ws;            // [64][32][64] fp32 = 512 KiB scratch

  dim3 grid(BLK_PER_N, N);                  // 2048 blocks x 256 threads
  scores_partial_kernel<<<grid, 256, 0, stream>>>(q, k, partial);
  out_kernel<<<grid, 256, 0, stream>>>(q, partial, out);
}